// Round 4
// baseline (103.463 us; speedup 1.0000x reference)
//
#include <hip/hip_runtime.h>
#include <math.h>

// GMMflow_fast: B=2048, M=1024, D=64.  MFMA formulation (R4):
//   GEMM1: C1[b,m] = sum_k A1[b,k]*B1[m,k], K=128: A1=[x^2 | x], B1=[a | p']
//          logw = -0.5*(C1 + q[m]);  w = exp(clip(logw))*Lam[m]
//   GEMM2: C3[b,n] = sum_m W[b,m]*V[m,n], N=144: V=[K | g | 1 | pad]
//   u[b,d] = (x*C3[:,d] + C3[:,64+d]) / C3[:,128]
// bf16 hi/lo split, 3 MFMA passes (AhBh + AhBl + AlBh): products exact in f32
// accumulate; dropped AlBl term ~2^-16 relative -> logw err ~5e-3. No f32 MFMA
// on CDNA4; single bf16 (2^-9) would give e^0.4 weight error -> hi/lo required.

#define B_N 2048
#define M_N 1024
#define NSPLIT 16
#define BT 128             // b per main block
#define MS 64              // m per split
#define PROW 132

typedef short bf16x8 __attribute__((ext_vector_type(8)));
typedef float f32x4 __attribute__((ext_vector_type(4)));

static __device__ __forceinline__ unsigned short bf16rn(float f) {
    union { float f; unsigned u; } v; v.f = f;
    unsigned r = v.u + 0x7FFF + ((v.u >> 16) & 1);
    return (unsigned short)(r >> 16);
}
static __device__ __forceinline__ float bf2f(unsigned short h) {
    union { unsigned u; float f; } v; v.u = ((unsigned)h) << 16;
    return v.f;
}

// ---------------- prep: component math + hi/lo split + layout builds ----------------
// blocks 0..15:  component precompute, 64 m each; writes B1h/l, VT h/l (K,g), q
// blocks 16..527: A1 build from X (y=x^2, x)
// block 528:     VT row 128 = ones (norm column)
__global__ __launch_bounds__(256)
void prep_kernel(const float* __restrict__ X,
                 const float* __restrict__ Mu0, const float* __restrict__ Mu1,
                 const float* __restrict__ S0, const float* __restrict__ S1,
                 const float* __restrict__ T, const float* __restrict__ E,
                 unsigned short* __restrict__ A1h, unsigned short* __restrict__ A1l,
                 unsigned short* __restrict__ B1h, unsigned short* __restrict__ B1l,
                 unsigned short* __restrict__ VTh, unsigned short* __restrict__ VTl,
                 float* __restrict__ qArr) {
    const int tid = threadIdx.x;
    if (blockIdx.x < 16) {
        __shared__ float sKf[64 * 65];
        __shared__ float sGf[64 * 65];
        const int m0 = blockIdx.x * 64;
        const float t = T[0], e = E[0];
        const float eps2 = e * e, eps4 = eps2 * eps2, omt = 1.f - t;
        const int d = tid & 63;
        #pragma unroll 4
        for (int it = 0; it < 16; it++) {
            int mi = it * 4 + (tid >> 6);
            int m = m0 + mi;
            int idx = m * 64 + d;
            float s0 = S0[idx], s1 = S1[idx];
            float mu0 = Mu0[idx], mu1 = Mu1[idx];
            float Ds = sqrtf(4.f * s0 * s1 + eps4);
            float Cs = 0.5f * (Ds - eps2);
            float sig = omt * omt * s0 + t * t * s1 + 2.f * t * omt * (Cs + 0.5f * eps2);
            float St = (t * s1 + omt * Cs) - (omt * s0 + t * Cs) - eps2 * t;
            float a = 1.f / sig;
            float K = St * a;
            float mut = omt * mu0 + t * mu1;
            float pp = -2.f * mut * a;
            float g = (mu1 - mu0) - K * mut;
            unsigned short ah = bf16rn(a);
            B1h[m * 128 + d] = ah;
            B1l[m * 128 + d] = bf16rn(a - bf2f(ah));
            unsigned short ph = bf16rn(pp);
            B1h[m * 128 + 64 + d] = ph;
            B1l[m * 128 + 64 + d] = bf16rn(pp - bf2f(ph));
            sKf[mi * 65 + d] = K;
            sGf[mi * 65 + d] = g;
            float qd = mut * mut * a + logf(sig);
            #pragma unroll
            for (int off = 32; off > 0; off >>= 1) qd += __shfl_xor(qd, off, 64);
            if (d == 0) qArr[m] = qd;
        }
        __syncthreads();
        // transposed V write: VT[n][m], coalesced over m
        #pragma unroll 4
        for (int it = 0; it < 32; it++) {
            int i = it * 256 + tid;          // 128 n x 64 m
            int n = i >> 6, mm = i & 63;
            float v = (n < 64) ? sKf[mm * 65 + n] : sGf[mm * 65 + (n - 64)];
            unsigned short h = bf16rn(v);
            VTh[n * 1024 + m0 + mm] = h;
            VTl[n * 1024 + m0 + mm] = bf16rn(v - bf2f(h));
        }
    } else if (blockIdx.x < 528) {
        int gid = (blockIdx.x - 16) * 256 + tid;   // 131072 = 2048 b x 64 d
        int b = gid >> 6, d = gid & 63;
        float x = X[gid];
        float y = x * x;
        unsigned short yh = bf16rn(y);
        A1h[b * 128 + d] = yh;
        A1l[b * 128 + d] = bf16rn(y - bf2f(yh));
        unsigned short xh = bf16rn(x);
        A1h[b * 128 + 64 + d] = xh;
        A1l[b * 128 + 64 + d] = bf16rn(x - bf2f(xh));
    } else {
        #pragma unroll
        for (int it = 0; it < 4; it++) {
            int m = it * 256 + tid;
            VTh[128 * 1024 + m] = 0x3F80;   // bf16(1.0)
            VTl[128 * 1024 + m] = 0;
        }
    }
}

// ---------------- main: GEMM1 -> exp -> GEMM2, all MFMA ----------------
// grid (16,16) = 256 blocks, 256 thr, ~102.5 KB LDS, 1 block/CU.
// wave tiles: GEMM1 32b x 64m (2x4 Ctiles); GEMM2 32b x 144n (2x9 Ctiles).
__global__ __launch_bounds__(256, 1)
void gmm_main_kernel(const float* __restrict__ Lam,
                     const unsigned short* __restrict__ A1h, const unsigned short* __restrict__ A1l,
                     const unsigned short* __restrict__ B1h, const unsigned short* __restrict__ B1l,
                     const unsigned short* __restrict__ VTh, const unsigned short* __restrict__ VTl,
                     const float* __restrict__ qArr, float* __restrict__ part) {
    // LDS (ushort units): region1: sA1h[128x136], sA1l  (V h/l overlays after GEMM1)
    //                     region2: sB1h[64x136], sB1l   (W h/l overlays, stride 68)
    __shared__ __align__(16) char smem_raw[104960];
    unsigned short* sm = (unsigned short*)smem_raw;
    unsigned short* sA1h = sm;                 // 17408
    unsigned short* sA1l = sm + 17408;         // 17408  (region1 end 34816)
    unsigned short* sVh  = sm;                 // 10368 (overlay)
    unsigned short* sVl  = sm + 10368;         // 10368
    unsigned short* sB1h = sm + 34816;         // 8704
    unsigned short* sB1l = sm + 43520;         // 8704   (region2 end 52224)
    unsigned short* sWh  = sm + 34816;         // 8704 (overlay, stride 68)
    unsigned short* sWl  = sm + 43520;         // 8704
    float* sQ = (float*)(smem_raw + 104448);   // 64
    float* sL = (float*)(smem_raw + 104704);   // 64

    const int tid  = threadIdx.x;
    const int Boff = blockIdx.x * BT;
    const int Moff = blockIdx.y * MS;
    const int w    = tid >> 6;
    const int lane = tid & 63;
    const int c = lane & 15, q = lane >> 4;

    // ---- stage A1 (128 rows x 256B, pad to 272B) and B1 (64 rows) ----
    {
        const float4* gAh = (const float4*)A1h + (size_t)Boff * 16;
        const float4* gAl = (const float4*)A1l + (size_t)Boff * 16;
        #pragma unroll
        for (int it = 0; it < 8; it++) {
            int i = it * 256 + tid;
            int row = i >> 4, cc = i & 15;
            *(float4*)(sA1h + row * 136 + cc * 8) = gAh[row * 16 + cc];
            *(float4*)(sA1l + row * 136 + cc * 8) = gAl[row * 16 + cc];
        }
        const float4* gBh = (const float4*)B1h + (size_t)Moff * 16;
        const float4* gBl = (const float4*)B1l + (size_t)Moff * 16;
        #pragma unroll
        for (int it = 0; it < 4; it++) {
            int i = it * 256 + tid;
            int row = i >> 4, cc = i & 15;
            *(float4*)(sB1h + row * 136 + cc * 8) = gBh[row * 16 + cc];
            *(float4*)(sB1l + row * 136 + cc * 8) = gBl[row * 16 + cc];
        }
        if (tid < 64) sQ[tid] = qArr[Moff + tid];
        else if (tid < 128) sL[tid - 64] = Lam[Moff + tid - 64];
    }
    __syncthreads();

    // ---- GEMM1: C1[128b x 64m], K=128, 3 hi/lo passes ----
    f32x4 acc1[2][4];
    #pragma unroll
    for (int i = 0; i < 2; i++)
        #pragma unroll
        for (int j = 0; j < 4; j++) acc1[i][j] = (f32x4){0.f, 0.f, 0.f, 0.f};
    {
        #pragma unroll
        for (int ks = 0; ks < 4; ks++) {
            bf16x8 Ah[2], Al[2], Bh[4], Bl[4];
            #pragma unroll
            for (int i = 0; i < 2; i++) {
                int row = (2 * w + i) * 16 + c;
                Ah[i] = *(const bf16x8*)(sA1h + row * 136 + ks * 32 + q * 8);
                Al[i] = *(const bf16x8*)(sA1l + row * 136 + ks * 32 + q * 8);
            }
            #pragma unroll
            for (int j = 0; j < 4; j++) {
                int row = j * 16 + c;
                Bh[j] = *(const bf16x8*)(sB1h + row * 136 + ks * 32 + q * 8);
                Bl[j] = *(const bf16x8*)(sB1l + row * 136 + ks * 32 + q * 8);
            }
            #pragma unroll
            for (int i = 0; i < 2; i++)
                #pragma unroll
                for (int j = 0; j < 4; j++) {
                    acc1[i][j] = __builtin_amdgcn_mfma_f32_16x16x32_bf16(Ah[i], Bh[j], acc1[i][j], 0, 0, 0);
                    acc1[i][j] = __builtin_amdgcn_mfma_f32_16x16x32_bf16(Ah[i], Bl[j], acc1[i][j], 0, 0, 0);
                    acc1[i][j] = __builtin_amdgcn_mfma_f32_16x16x32_bf16(Al[i], Bh[j], acc1[i][j], 0, 0, 0);
                }
        }
    }
    __syncthreads();   // A1/B1 reads done -> overlays safe

    // ---- stage V (overlay region1) + compute W (overlay region2) ----
    {
        const float4* gVh = (const float4*)VTh;   // row stride 128 f4
        const float4* gVl = (const float4*)VTl;
        int mo8 = Moff >> 3;
        #pragma unroll
        for (int it = 0; it < 5; it++) {
            int i = it * 256 + tid;               // 144 n x 8 f4
            if (i < 1152) {
                int row = i >> 3, cc = i & 7;
                *(float4*)(sVh + row * 72 + cc * 8) = gVh[row * 128 + mo8 + cc];
                *(float4*)(sVl + row * 72 + cc * 8) = gVl[row * 128 + mo8 + cc];
            }
        }
        // W: C/D layout col=lane&15 (m), row=q*4+reg (b)
        #pragma unroll
        for (int i = 0; i < 2; i++)
            #pragma unroll
            for (int j = 0; j < 4; j++) {
                int m = j * 16 + c;
                float qm = sQ[m], lm = sL[m];
                #pragma unroll
                for (int r = 0; r < 4; r++) {
                    int bl = (2 * w + i) * 16 + q * 4 + r;
                    float lw = -0.5f * (acc1[i][j][r] + qm);
                    lw = fminf(50.f, fmaxf(-50.f, lw));
                    float wf = __expf(lw) * lm;
                    unsigned short wh = bf16rn(wf);
                    sWh[bl * 68 + m] = wh;
                    sWl[bl * 68 + m] = bf16rn(wf - bf2f(wh));
                }
            }
    }
    __syncthreads();

    // ---- GEMM2: C3[128b x 144n], K=64 (m), 3 hi/lo passes ----
    f32x4 acc2[2][9];
    #pragma unroll
    for (int i = 0; i < 2; i++)
        #pragma unroll
        for (int j = 0; j < 9; j++) acc2[i][j] = (f32x4){0.f, 0.f, 0.f, 0.f};
    {
        #pragma unroll
        for (int ks = 0; ks < 2; ks++) {
            bf16x8 Wh[2], Wl[2], Vh[9], Vl[9];
            #pragma unroll
            for (int i = 0; i < 2; i++) {
                int row = (2 * w + i) * 16 + c;
                Wh[i] = *(const bf16x8*)(sWh + row * 68 + ks * 32 + q * 8);
                Wl[i] = *(const bf16x8*)(sWl + row * 68 + ks * 32 + q * 8);
            }
            #pragma unroll
            for (int j = 0; j < 9; j++) {
                int row = j * 16 + c;
                Vh[j] = *(const bf16x8*)(sVh + row * 72 + ks * 32 + q * 8);
                Vl[j] = *(const bf16x8*)(sVl + row * 72 + ks * 32 + q * 8);
            }
            #pragma unroll
            for (int i = 0; i < 2; i++)
                #pragma unroll
                for (int j = 0; j < 9; j++) {
                    acc2[i][j] = __builtin_amdgcn_mfma_f32_16x16x32_bf16(Wh[i], Vh[j], acc2[i][j], 0, 0, 0);
                    acc2[i][j] = __builtin_amdgcn_mfma_f32_16x16x32_bf16(Wh[i], Vl[j], acc2[i][j], 0, 0, 0);
                    acc2[i][j] = __builtin_amdgcn_mfma_f32_16x16x32_bf16(Wl[i], Vh[j], acc2[i][j], 0, 0, 0);
                }
        }
    }

    // ---- epilogue: partials [split][b][132]: n<128 = S1|S2, n=128 = norm ----
    {
        #pragma unroll
        for (int i = 0; i < 2; i++)
            #pragma unroll
            for (int j = 0; j < 9; j++) {
                #pragma unroll
                for (int r = 0; r < 4; r++) {
                    int bl = (2 * w + i) * 16 + q * 4 + r;
                    int n = j * 16 + c;
                    float* row = part + ((size_t)blockIdx.y * B_N + Boff + bl) * PROW;
                    if (j < 8) row[n] = acc2[i][j][r];
                    else if (c == 0) row[128] = acc2[i][j][r];
                }
            }
    }
}

// ---------------- finalize: reduce splits ----------------
__global__ __launch_bounds__(256)
void finalize_kernel(const float* __restrict__ X, const float* __restrict__ part,
                     float* __restrict__ out) {
    int gid = blockIdx.x * 256 + threadIdx.x;   // 131072
    int b = gid >> 6, d = gid & 63;
    float a1 = 0.f, a2 = 0.f, nn = 0.f;
    #pragma unroll
    for (int s = 0; s < NSPLIT; s++) {
        const float* row = part + ((size_t)s * B_N + b) * PROW;
        a1 += row[d];
        a2 += row[64 + d];
        nn += row[128];
    }
    out[gid] = (X[gid] * a1 + a2) / nn;
}

extern "C" void kernel_launch(void* const* d_in, const int* in_sizes, int n_in,
                              void* d_out, int out_size, void* d_ws, size_t ws_size,
                              hipStream_t stream) {
    (void)in_sizes; (void)n_in; (void)out_size; (void)ws_size;
    const float* X   = (const float*)d_in[0];
    const float* Mu0 = (const float*)d_in[1];
    const float* Mu1 = (const float*)d_in[2];
    const float* S0  = (const float*)d_in[3];
    const float* S1  = (const float*)d_in[4];
    const float* Lam = (const float*)d_in[5];
    const float* T   = (const float*)d_in[6];
    const float* E   = (const float*)d_in[7];

    char* ws = (char*)d_ws;
    unsigned short* A1h = (unsigned short*)(ws);                 // 512 KB
    unsigned short* A1l = (unsigned short*)(ws + 524288);        // 512 KB
    unsigned short* B1h = (unsigned short*)(ws + 1048576);       // 256 KB
    unsigned short* B1l = (unsigned short*)(ws + 1310720);       // 256 KB
    unsigned short* VTh = (unsigned short*)(ws + 1572864);       // 288 KB
    unsigned short* VTl = (unsigned short*)(ws + 1867776);       // 288 KB
    float* qArr = (float*)(ws + 2162688);                        // 4 KB
    float* part = (float*)(ws + 2166784);                        // 17.3 MB

    prep_kernel<<<529, 256, 0, stream>>>(X, Mu0, Mu1, S0, S1, T, E,
                                         A1h, A1l, B1h, B1l, VTh, VTl, qArr);
    dim3 grid(B_N / BT, NSPLIT);
    gmm_main_kernel<<<grid, 256, 0, stream>>>(Lam, A1h, A1l, B1h, B1l, VTh, VTl, qArr, part);
    finalize_kernel<<<512, 256, 0, stream>>>(X, part, (float*)d_out);
}

// Round 5
// 90.075 us; speedup vs baseline: 1.1486x; 1.1486x over previous
//
#include <hip/hip_runtime.h>
#include <math.h>

// GMMflow_fast: B=2048, M=1024, D=64.  MFMA formulation, R5.
//   GEMM1 (3-pass bf16 hi/lo, K=128): C1[b,m] = sum_k A1[b,k]*B1[m,k],
//          A1=[x^2|x] (built in-kernel), B1=[a|p'];  logw=-0.5*(C1+q[m])
//   w = exp(clip(logw))*Lam;  norm via shfl-reduce of bf16-rounded w (consistent)
//   GEMM2 (single-pass bf16, K=64m, N=128): C3[b,n] = sum_m W[b,m]*V[m,n], V=[K|g]
//   u[b,d] = (x*C3[:,d] + C3[:,64+d]) / norm
// BT=64, grid(32,16)=512 blocks, ~70 KB LDS -> 2 blocks/CU, 8 waves/CU.

#define B_N 2048
#define M_N 1024
#define NSPLIT 16
#define BT 64
#define MS 64
#define PROW 132   // 64 S1 | 64 S2 | norm0 norm1 | pad

typedef short bf16x8 __attribute__((ext_vector_type(8)));
typedef float f32x4 __attribute__((ext_vector_type(4)));

static __device__ __forceinline__ unsigned short bf16rn(float f) {
    union { float f; unsigned u; } v; v.f = f;
    unsigned r = v.u + 0x7FFF + ((v.u >> 16) & 1);
    return (unsigned short)(r >> 16);
}
static __device__ __forceinline__ float bf2f(unsigned short h) {
    union { unsigned u; float f; } v; v.u = ((unsigned)h) << 16;
    return v.f;
}
static __device__ __forceinline__ void st4(unsigned short* p, unsigned short a,
                                           unsigned short b, unsigned short c, unsigned short d) {
    union { unsigned short u[4]; float2 f; } t;
    t.u[0] = a; t.u[1] = b; t.u[2] = c; t.u[3] = d;
    *(float2*)p = t.f;
}

// ---------------- prep: 64 blocks x 16 m of component math ----------------
__global__ __launch_bounds__(256)
void prep_kernel(const float* __restrict__ Mu0, const float* __restrict__ Mu1,
                 const float* __restrict__ S0, const float* __restrict__ S1,
                 const float* __restrict__ T, const float* __restrict__ E,
                 unsigned short* __restrict__ B1h, unsigned short* __restrict__ B1l,
                 unsigned short* __restrict__ VTh, float* __restrict__ qArr) {
    __shared__ float sK[16 * 65];
    __shared__ float sG[16 * 65];
    const int tid = threadIdx.x;
    const int m0 = blockIdx.x * 16;
    const float t = T[0], e = E[0];
    const float eps2 = e * e, eps4 = eps2 * eps2, omt = 1.f - t;
    const int d = tid & 63;
    #pragma unroll
    for (int it = 0; it < 4; it++) {
        int mi = it * 4 + (tid >> 6);
        int m = m0 + mi;
        int idx = m * 64 + d;
        float s0 = S0[idx], s1 = S1[idx];
        float mu0 = Mu0[idx], mu1 = Mu1[idx];
        float Ds = sqrtf(4.f * s0 * s1 + eps4);
        float Cs = 0.5f * (Ds - eps2);
        float sig = omt * omt * s0 + t * t * s1 + 2.f * t * omt * (Cs + 0.5f * eps2);
        float St = (t * s1 + omt * Cs) - (omt * s0 + t * Cs) - eps2 * t;
        float a = 1.f / sig;
        float K = St * a;
        float mut = omt * mu0 + t * mu1;
        float pp = -2.f * mut * a;
        float g = (mu1 - mu0) - K * mut;
        unsigned short ah = bf16rn(a);
        B1h[m * 128 + d] = ah;
        B1l[m * 128 + d] = bf16rn(a - bf2f(ah));
        unsigned short ph = bf16rn(pp);
        B1h[m * 128 + 64 + d] = ph;
        B1l[m * 128 + 64 + d] = bf16rn(pp - bf2f(ph));
        sK[mi * 65 + d] = K;
        sG[mi * 65 + d] = g;
        float qd = mut * mut * a + logf(sig);
        #pragma unroll
        for (int off = 32; off > 0; off >>= 1) qd += __shfl_xor(qd, off, 64);
        if (d == 0) qArr[m] = qd;
    }
    __syncthreads();
    // VT[n][m] transpose write (n<128: K then g)
    #pragma unroll
    for (int it = 0; it < 8; it++) {
        int i = it * 256 + tid;        // 128 n x 16 m
        int n = i >> 4, mm = i & 15;
        float v = (n < 64) ? sK[mm * 65 + n] : sG[mm * 65 + (n - 64)];
        VTh[n * M_N + m0 + mm] = bf16rn(v);
    }
}

// ---------------- main ----------------
// grid (32,16), 256 thr, 70.2 KB LDS, 2 blocks/CU.
__global__ __launch_bounds__(256, 2)
void gmm_main_kernel(const float* __restrict__ X, const float* __restrict__ Lam,
                     const unsigned short* __restrict__ B1h, const unsigned short* __restrict__ B1l,
                     const unsigned short* __restrict__ VTh,
                     const float* __restrict__ qArr, float* __restrict__ part) {
    // ushort regions: sA1h[64x136) sA1l sB1h[64x136] sB1l  (34816 us total)
    // overlays after GEMM1: sV[128x72] over A-region, sW[64x72] over B-region
    __shared__ __align__(16) char smem_raw[70144];
    unsigned short* sm = (unsigned short*)smem_raw;
    unsigned short* sA1h = sm;                // 8704
    unsigned short* sA1l = sm + 8704;         // 8704
    unsigned short* sB1h = sm + 17408;        // 8704
    unsigned short* sB1l = sm + 26112;        // 8704
    unsigned short* sV   = sm;                // overlay, 9216
    unsigned short* sW   = sm + 17408;        // overlay, 4608
    float* sQ = (float*)(smem_raw + 69632);   // 64
    float* sL = (float*)(smem_raw + 69888);   // 64

    const int tid  = threadIdx.x;
    const int Boff = blockIdx.x * BT;
    const int Moff = blockIdx.y * MS;
    const int w    = tid >> 6;
    const int lane = tid & 63;
    const int c = lane & 15, q = lane >> 4;
    const int wb = w >> 1;     // b-half
    const int wm = w & 1;      // GEMM1 m-half / GEMM2 n-half

    // ---- stage: build A1 from X (hi/lo split of x^2, x); copy B1 h/l ----
    {
        const float4* X4 = (const float4*)X;
        #pragma unroll
        for (int it = 0; it < 4; it++) {
            int i = it * 256 + tid;            // 64 b x 16 f4
            int b = i >> 4, dq = i & 15;
            float4 xv = X4[(size_t)(Boff + b) * 16 + dq];
            float xs[4] = {xv.x, xv.y, xv.z, xv.w};
            unsigned short yh[4], yl[4], xh[4], xl[4];
            #pragma unroll
            for (int k = 0; k < 4; k++) {
                float y = xs[k] * xs[k];
                yh[k] = bf16rn(y);  yl[k] = bf16rn(y - bf2f(yh[k]));
                xh[k] = bf16rn(xs[k]);  xl[k] = bf16rn(xs[k] - bf2f(xh[k]));
            }
            int base = b * 136 + 4 * dq;
            st4(sA1h + base, yh[0], yh[1], yh[2], yh[3]);
            st4(sA1l + base, yl[0], yl[1], yl[2], yl[3]);
            st4(sA1h + base + 64, xh[0], xh[1], xh[2], xh[3]);
            st4(sA1l + base + 64, xl[0], xl[1], xl[2], xl[3]);
        }
        const float4* gBh = (const float4*)B1h + (size_t)Moff * 16;
        const float4* gBl = (const float4*)B1l + (size_t)Moff * 16;
        #pragma unroll
        for (int it = 0; it < 4; it++) {
            int i = it * 256 + tid;            // 64 m x 16 f4
            int row = i >> 4, cc = i & 15;
            *(float4*)(sB1h + row * 136 + cc * 8) = gBh[row * 16 + cc];
            *(float4*)(sB1l + row * 136 + cc * 8) = gBl[row * 16 + cc];
        }
        if (tid < 64) sQ[tid] = qArr[Moff + tid];
        else if (tid < 128) sL[tid - 64] = Lam[Moff + tid - 64];
    }
    __syncthreads();

    // ---- GEMM1: wave quadrant 32b x 32m, K=128, 3 hi/lo passes ----
    f32x4 acc1[2][2];
    #pragma unroll
    for (int i = 0; i < 2; i++)
        #pragma unroll
        for (int j = 0; j < 2; j++) acc1[i][j] = (f32x4){0.f, 0.f, 0.f, 0.f};
    #pragma unroll
    for (int ks = 0; ks < 4; ks++) {
        bf16x8 Ah[2], Al[2], Bh[2], Bl[2];
        #pragma unroll
        for (int i = 0; i < 2; i++) {
            int row = wb * 32 + i * 16 + c;
            Ah[i] = *(const bf16x8*)(sA1h + row * 136 + ks * 32 + q * 8);
            Al[i] = *(const bf16x8*)(sA1l + row * 136 + ks * 32 + q * 8);
        }
        #pragma unroll
        for (int j = 0; j < 2; j++) {
            int row = wm * 32 + j * 16 + c;
            Bh[j] = *(const bf16x8*)(sB1h + row * 136 + ks * 32 + q * 8);
            Bl[j] = *(const bf16x8*)(sB1l + row * 136 + ks * 32 + q * 8);
        }
        #pragma unroll
        for (int i = 0; i < 2; i++)
            #pragma unroll
            for (int j = 0; j < 2; j++) {
                acc1[i][j] = __builtin_amdgcn_mfma_f32_16x16x32_bf16(Ah[i], Bh[j], acc1[i][j], 0, 0, 0);
                acc1[i][j] = __builtin_amdgcn_mfma_f32_16x16x32_bf16(Ah[i], Bl[j], acc1[i][j], 0, 0, 0);
                acc1[i][j] = __builtin_amdgcn_mfma_f32_16x16x32_bf16(Al[i], Bh[j], acc1[i][j], 0, 0, 0);
            }
    }
    __syncthreads();   // A/B regions dead -> overlays

    // ---- stage V (single bf16) + compute W + consistent norm ----
    {
        const float4* gV = (const float4*)VTh;   // row stride 128 f4
        int mo8 = Moff >> 3;
        #pragma unroll
        for (int it = 0; it < 4; it++) {
            int i = it * 256 + tid;              // 128 n x 8 f4
            int row = i >> 3, cc = i & 7;
            *(float4*)(sV + row * 72 + cc * 8) = gV[(size_t)row * 128 + mo8 + cc];
        }
        float nsum[2][4];
        #pragma unroll
        for (int i = 0; i < 2; i++)
            #pragma unroll
            for (int r = 0; r < 4; r++) nsum[i][r] = 0.f;
        #pragma unroll
        for (int i = 0; i < 2; i++)
            #pragma unroll
            for (int j = 0; j < 2; j++) {
                int m = wm * 32 + j * 16 + c;
                float qm = sQ[m], lm = sL[m];
                #pragma unroll
                for (int r = 0; r < 4; r++) {
                    int bl = wb * 32 + i * 16 + q * 4 + r;
                    float lw = -0.5f * (acc1[i][j][r] + qm);
                    lw = fminf(50.f, fmaxf(-50.f, lw));
                    float wf = __expf(lw) * lm;
                    unsigned short wh = bf16rn(wf);
                    sW[bl * 72 + m] = wh;
                    nsum[i][r] += bf2f(wh);
                }
            }
        #pragma unroll
        for (int mask = 1; mask <= 8; mask <<= 1)
            #pragma unroll
            for (int i = 0; i < 2; i++)
                #pragma unroll
                for (int r = 0; r < 4; r++)
                    nsum[i][r] += __shfl_xor(nsum[i][r], mask, 64);
        if (c == 0) {
            #pragma unroll
            for (int i = 0; i < 2; i++)
                #pragma unroll
                for (int r = 0; r < 4; r++) {
                    int b = Boff + wb * 32 + i * 16 + q * 4 + r;
                    part[((size_t)blockIdx.y * B_N + b) * PROW + 128 + wm] = nsum[i][r];
                }
        }
    }
    __syncthreads();

    // ---- GEMM2: wave 32b x 64n, K=64, single pass ----
    f32x4 acc2[2][4];
    #pragma unroll
    for (int i = 0; i < 2; i++)
        #pragma unroll
        for (int j = 0; j < 4; j++) acc2[i][j] = (f32x4){0.f, 0.f, 0.f, 0.f};
    #pragma unroll
    for (int ks = 0; ks < 2; ks++) {
        bf16x8 Wf[2], Vf[4];
        #pragma unroll
        for (int i = 0; i < 2; i++) {
            int row = wb * 32 + i * 16 + c;
            Wf[i] = *(const bf16x8*)(sW + row * 72 + ks * 32 + q * 8);
        }
        #pragma unroll
        for (int j = 0; j < 4; j++) {
            int row = wm * 64 + j * 16 + c;
            Vf[j] = *(const bf16x8*)(sV + row * 72 + ks * 32 + q * 8);
        }
        #pragma unroll
        for (int i = 0; i < 2; i++)
            #pragma unroll
            for (int j = 0; j < 4; j++)
                acc2[i][j] = __builtin_amdgcn_mfma_f32_16x16x32_bf16(Wf[i], Vf[j], acc2[i][j], 0, 0, 0);
    }

    // ---- epilogue: S1|S2 partials ----
    #pragma unroll
    for (int i = 0; i < 2; i++)
        #pragma unroll
        for (int j = 0; j < 4; j++) {
            #pragma unroll
            for (int r = 0; r < 4; r++) {
                int b = Boff + wb * 32 + i * 16 + q * 4 + r;
                int n = wm * 64 + j * 16 + c;
                part[((size_t)blockIdx.y * B_N + b) * PROW + n] = acc2[i][j][r];
            }
        }
}

// ---------------- finalize ----------------
__global__ __launch_bounds__(256)
void finalize_kernel(const float* __restrict__ X, const float* __restrict__ part,
                     float* __restrict__ out) {
    int gid = blockIdx.x * 256 + threadIdx.x;   // 131072
    int b = gid >> 6, d = gid & 63;
    float a1 = 0.f, a2 = 0.f, nn = 0.f;
    #pragma unroll
    for (int s = 0; s < NSPLIT; s++) {
        const float* row = part + ((size_t)s * B_N + b) * PROW;
        a1 += row[d];
        a2 += row[64 + d];
        nn += row[128] + row[129];
    }
    out[gid] = (X[gid] * a1 + a2) / nn;
}

extern "C" void kernel_launch(void* const* d_in, const int* in_sizes, int n_in,
                              void* d_out, int out_size, void* d_ws, size_t ws_size,
                              hipStream_t stream) {
    (void)in_sizes; (void)n_in; (void)out_size; (void)ws_size;
    const float* X   = (const float*)d_in[0];
    const float* Mu0 = (const float*)d_in[1];
    const float* Mu1 = (const float*)d_in[2];
    const float* S0  = (const float*)d_in[3];
    const float* S1  = (const float*)d_in[4];
    const float* Lam = (const float*)d_in[5];
    const float* T   = (const float*)d_in[6];
    const float* E   = (const float*)d_in[7];

    char* ws = (char*)d_ws;
    unsigned short* B1h = (unsigned short*)(ws);             // 256 KB
    unsigned short* B1l = (unsigned short*)(ws + 262144);    // 256 KB
    unsigned short* VTh = (unsigned short*)(ws + 524288);    // 256 KB
    float* qArr = (float*)(ws + 786432);                     // 4 KB
    float* part = (float*)(ws + 790528);                     // 17.3 MB

    prep_kernel<<<64, 256, 0, stream>>>(Mu0, Mu1, S0, S1, T, E, B1h, B1l, VTh, qArr);
    dim3 grid(B_N / BT, NSPLIT);
    gmm_main_kernel<<<grid, 256, 0, stream>>>(X, Lam, B1h, B1l, VTh, qArr, part);
    finalize_kernel<<<512, 256, 0, stream>>>(X, part, (float*)d_out);
}